// Round 3
// baseline (187.292 us; speedup 1.0000x reference)
//
#include <hip/hip_runtime.h>

// GQA attention fused pipeline for MI355X (gfx950).
// cvt(fp32->bf16) -> GEMM(QKV proj) -> RoPE/scatter + V-transpose
// -> flash attention (swapped 32x32 MFMA, in-block split-K, XCD-swizzled)
// -> GEMM(out proj).

typedef __bf16 bf16x8 __attribute__((ext_vector_type(8)));
typedef float f32x4 __attribute__((ext_vector_type(4)));
typedef float f32x16 __attribute__((ext_vector_type(16)));
typedef int i32x4 __attribute__((ext_vector_type(4)));
typedef unsigned short ushort4v __attribute__((ext_vector_type(4)));
typedef unsigned short ushort8v __attribute__((ext_vector_type(8)));
typedef unsigned short u16;
typedef unsigned int u32;

#define DEVINL __device__ __forceinline__

DEVINL float bf2f(u16 u) {
  unsigned int x = ((unsigned int)u) << 16;
  return __builtin_bit_cast(float, x);
}
DEVINL u16 f2bf(float f) {  // RTNE
  unsigned int x = __builtin_bit_cast(unsigned int, f);
  x += 0x7fffu + ((x >> 16) & 1u);
  return (u16)(x >> 16);
}

constexpr int Bb = 2, Tt = 2048, Dd = 1024, QH = 16, KVH = 4, HD = 64;
// fold softmax scale (1/sqrt(64)) and log2(e) into Q so we can use exp2f
constexpr float SCALE_L2E = 0.125f * 1.44269504088896340736f;

// ---------------------------------------------------------------- convert
__global__ void cvt_f32_to_bf16(const float* __restrict__ in, u16* __restrict__ out, int n4) {
  int i = blockIdx.x * blockDim.x + threadIdx.x;
  if (i >= n4) return;
  float4 v = reinterpret_cast<const float4*>(in)[i];
  ushort4v o = {f2bf(v.x), f2bf(v.y), f2bf(v.z), f2bf(v.w)};
  reinterpret_cast<ushort4v*>(out)[i] = o;
}

// ---------------------------------------------------------------- GEMM C = A(M,K) @ B(N,K)^T
template <bool OUT_F32>
__global__ __launch_bounds__(256) void gemm_bt(const u16* __restrict__ A,
                                               const u16* __restrict__ Bw,
                                               void* __restrict__ Cout, int M, int N, int K) {
  __shared__ alignas(16) u16 lA[128 * 64];
  __shared__ alignas(16) u16 lB[128 * 64];
  const int tid = threadIdx.x;
  const int w = tid >> 6, lane = tid & 63;
  const int r16 = lane & 15, g4 = lane >> 4;
  const int row0 = blockIdx.y * 128, col0 = blockIdx.x * 128;
  const int sr = tid >> 3, sc = tid & 7;
  const int NT = K >> 6;

  bf16x8 ra[4], rb[4];
  f32x4 acc[4][4];
#pragma unroll
  for (int i = 0; i < 4; ++i)
#pragma unroll
    for (int j = 0; j < 4; ++j) acc[i][j] = f32x4{0.f, 0.f, 0.f, 0.f};

  const int wm = (w >> 1) * 64, wn = (w & 1) * 64;

#pragma unroll
  for (int i = 0; i < 4; ++i) {
    int r = i * 32 + sr;
    ra[i] = *reinterpret_cast<const bf16x8*>(A + (size_t)(row0 + r) * K + sc * 8);
    rb[i] = *reinterpret_cast<const bf16x8*>(Bw + (size_t)(col0 + r) * K + sc * 8);
  }

  for (int kt = 0; kt < NT; ++kt) {
    __syncthreads();
#pragma unroll
    for (int i = 0; i < 4; ++i) {
      int r = i * 32 + sr;
      int c = (sc ^ (r & 7)) * 8;
      *reinterpret_cast<bf16x8*>(&lA[r * 64 + c]) = ra[i];
      *reinterpret_cast<bf16x8*>(&lB[r * 64 + c]) = rb[i];
    }
    __syncthreads();
    if (kt + 1 < NT) {
      int k0 = (kt + 1) << 6;
#pragma unroll
      for (int i = 0; i < 4; ++i) {
        int r = i * 32 + sr;
        ra[i] = *reinterpret_cast<const bf16x8*>(A + (size_t)(row0 + r) * K + k0 + sc * 8);
        rb[i] = *reinterpret_cast<const bf16x8*>(Bw + (size_t)(col0 + r) * K + k0 + sc * 8);
      }
    }
#pragma unroll
    for (int kk = 0; kk < 2; ++kk) {
      bf16x8 af[4], bfr[4];
#pragma unroll
      for (int mf = 0; mf < 4; ++mf) {
        int r = wm + mf * 16 + r16;
        int c = ((kk * 4 + g4) ^ (r & 7)) * 8;
        af[mf] = *reinterpret_cast<const bf16x8*>(&lA[r * 64 + c]);
      }
#pragma unroll
      for (int nf = 0; nf < 4; ++nf) {
        int r = wn + nf * 16 + r16;
        int c = ((kk * 4 + g4) ^ (r & 7)) * 8;
        bfr[nf] = *reinterpret_cast<const bf16x8*>(&lB[r * 64 + c]);
      }
#pragma unroll
      for (int mf = 0; mf < 4; ++mf)
#pragma unroll
        for (int nf = 0; nf < 4; ++nf)
          acc[mf][nf] =
              __builtin_amdgcn_mfma_f32_16x16x32_bf16(af[mf], bfr[nf], acc[mf][nf], 0, 0, 0);
    }
  }

#pragma unroll
  for (int mf = 0; mf < 4; ++mf)
#pragma unroll
    for (int nf = 0; nf < 4; ++nf)
#pragma unroll
      for (int r = 0; r < 4; ++r) {
        size_t row = (size_t)(row0 + wm + mf * 16 + g4 * 4 + r);
        size_t col = (size_t)(col0 + wn + nf * 16 + r16);
        float v = acc[mf][nf][r];
        if (OUT_F32)
          reinterpret_cast<float*>(Cout)[row * N + col] = v;
        else
          reinterpret_cast<u16*>(Cout)[row * N + col] = f2bf(v);
      }
}

// ---------------------------------------------------------------- RoPE + scatter (q and k)
__global__ void rope_scatter(const u16* __restrict__ P, const float* __restrict__ cosT,
                             const float* __restrict__ sinT, u16* __restrict__ Q,
                             u16* __restrict__ Kc) {
  int idx = blockIdx.x * 256 + threadIdx.x;
  if (idx >= (Bb * Tt) * 640) return;
  int row = idx / 640, p = idx - row * 640;
  int b = row >> 11, t = row & 2047;
  int n, d;
  u16* outp;
  float scl;
  if (p < 512) {
    n = p * 2;
    int h = n >> 6;
    d = n & 63;
    outp = Q + ((size_t)(b * QH + h) * Tt + t) * HD + d;
    scl = SCALE_L2E;
  } else {
    int r2 = p - 512;
    int kvh = r2 >> 5, dp = r2 & 31;
    d = dp * 2;
    n = 1024 + kvh * 128 + d;
    outp = Kc + ((size_t)(b * KVH + kvh) * Tt + t) * HD + d;
    scl = 1.0f;
  }
  unsigned int pv = *reinterpret_cast<const unsigned int*>(P + (size_t)row * 1536 + n);
  float v0 = bf2f((u16)(pv & 0xffffu)), v1 = bf2f((u16)(pv >> 16));
  float c = cosT[t * HD + d], s = sinT[t * HD + d];
  float o0 = (v0 * c - v1 * s) * scl;
  float o1 = (v1 * c + v0 * s) * scl;
  unsigned int ob = (unsigned int)f2bf(o0) | ((unsigned int)f2bf(o1) << 16);
  *reinterpret_cast<unsigned int*>(outp) = ob;
}

// ---------------------------------------------------------------- V transpose: Vt[bh][d][t]
__global__ void v_transpose(const u16* __restrict__ P, u16* __restrict__ Vt) {
  __shared__ u16 tile[64][72];
  int bh = blockIdx.y;
  int b = bh >> 2, kvh = bh & 3;
  int t0 = blockIdx.x * 64;
  int tid = threadIdx.x;
  int colbase = 1024 + kvh * 128 + 64;
#pragma unroll
  for (int j = 0; j < 4; ++j) {
    int rr = j * 16 + (tid >> 4);
    int cc = (tid & 15) * 4;
    *reinterpret_cast<uint2*>(&tile[rr][cc]) =
        *reinterpret_cast<const uint2*>(P + (size_t)(b * Tt + t0 + rr) * 1536 + colbase + cc);
  }
  __syncthreads();
  int d = tid >> 2, seg = tid & 3;
  size_t obase = ((size_t)bh * HD + d) * Tt + t0 + seg * 16;
#pragma unroll
  for (int jj = 0; jj < 2; ++jj) {
    ushort8v v;
#pragma unroll
    for (int i = 0; i < 8; ++i) v[i] = tile[seg * 16 + jj * 8 + i][d];
    *reinterpret_cast<ushort8v*>(Vt + obase + jj * 8) = v;
  }
}

// ---------------------------------------------------------------- flash attention v3
// 8 waves / 512 threads: wave = (spl, qsub); spl in {0,1} halves the key range
// (in-block split-K), qsub picks 32 q-rows of the block's 128. Swapped-operand
// 32x32 MFMA softmax stays fully per-lane; split halves merged via padded LDS.
// Grid is 1-D, XCD-swizzled so xcd == (b,kvh): K/V (1MB) stays L2-resident.
__global__ __launch_bounds__(512) void attn_fwd3(const u16* __restrict__ Q,
                                                 const u16* __restrict__ Kc,
                                                 const u16* __restrict__ Vt,
                                                 u16* __restrict__ Oa) {
  __shared__ alignas(16) float cmb[4][32][66];  // split-1 partials: O^T + m + l
  __shared__ alignas(16) u16 ot[4][32][72];     // final bf16 O, pre-store transpose
  const int tid = threadIdx.x;
  const int w = tid >> 6, lane = tid & 63;
  const int qsub = w & 3, spl = w >> 2;
  const int l31 = lane & 31, hi = lane >> 5;

  // XCD swizzle: fid&7 selects (b,kvh) so each XCD's L2 owns one K/V set.
  const int fid = blockIdx.x;
  const int xcd = fid & 7, idx = fid >> 3;
  const int b = xcd >> 2, kvh = xcd & 3;
  const int g = idx & 3, qblk = idx >> 2;
  const int h = kvh * 4 + g;
  const int t0 = qblk * 128 + qsub * 32;

  const u16* Qh = Q + ((size_t)(b * QH + h) * Tt + t0 + l31) * HD + hi * 8;
  const u16* Kh = Kc + (size_t)(b * KVH + kvh) * Tt * HD;
  const u16* Vh = Vt + (size_t)(b * KVH + kvh) * HD * Tt;

  // Q as B-fragment: col = t = lane&31, k = kf*16 + hi*8 + j (Q pre-scaled)
  bf16x8 qf[4];
#pragma unroll
  for (int kf = 0; kf < 4; ++kf)
    qf[kf] = *reinterpret_cast<const bf16x8*>(Qh + kf * 16);

  f32x16 oacc[2];
#pragma unroll
  for (int df = 0; df < 2; ++df)
#pragma unroll
    for (int r = 0; r < 16; ++r) oacc[df][r] = 0.f;
  float mrun = -__builtin_inff(), lp = 0.f;

  const int sbeg = spl * 1024, send = sbeg + 1024;
  for (int s0 = sbeg; s0 < send; s0 += 64) {
    bf16x8 kfr[2][4];
#pragma unroll
    for (int sb = 0; sb < 2; ++sb) {
      const u16* Kb = Kh + (size_t)(s0 + sb * 32 + l31) * HD + hi * 8;
#pragma unroll
      for (int kf = 0; kf < 4; ++kf)
        kfr[sb][kf] = *reinterpret_cast<const bf16x8*>(Kb + kf * 16);
    }
    f32x16 sacc[2];
    __builtin_amdgcn_s_setprio(1);
#pragma unroll
    for (int sb = 0; sb < 2; ++sb) {
#pragma unroll
      for (int r = 0; r < 16; ++r) sacc[sb][r] = 0.f;
#pragma unroll
      for (int kf = 0; kf < 4; ++kf)
        sacc[sb] = __builtin_amdgcn_mfma_f32_32x32x16_bf16(kfr[sb][kf], qf[kf], sacc[sb], 0, 0, 0);
    }
    __builtin_amdgcn_s_setprio(0);

    // V loads issued early; latency hides under softmax.
    bf16x8 vf[2][2][2];  // [df][sb][ks]
#pragma unroll
    for (int df = 0; df < 2; ++df)
#pragma unroll
      for (int sb = 0; sb < 2; ++sb)
#pragma unroll
        for (int ks = 0; ks < 2; ++ks)
          vf[df][sb][ks] = *reinterpret_cast<const bf16x8*>(
              Vh + (size_t)(df * 32 + l31) * Tt + s0 + sb * 32 + ks * 16 + hi * 8);

    // ---- online softmax, per-lane (column t = lane&31) ----
    float m0 = fmaxf(sacc[0][0], sacc[0][1]), m1 = fmaxf(sacc[0][2], sacc[0][3]);
    float m2 = fmaxf(sacc[0][4], sacc[0][5]), m3 = fmaxf(sacc[0][6], sacc[0][7]);
#pragma unroll
    for (int r = 8; r < 16; r += 4) {
      m0 = fmaxf(m0, fmaxf(sacc[0][r], sacc[0][r + 1]));
      m1 = fmaxf(m1, fmaxf(sacc[0][r + 2], sacc[0][r + 3]));
    }
#pragma unroll
    for (int r = 0; r < 16; r += 4) {
      m2 = fmaxf(m2, fmaxf(sacc[1][r], sacc[1][r + 1]));
      m3 = fmaxf(m3, fmaxf(sacc[1][r + 2], sacc[1][r + 3]));
    }
    float tm = fmaxf(fmaxf(m0, m1), fmaxf(m2, m3));
    tm = fmaxf(tm, __shfl_xor(tm, 32));

    // defer-max (T13): only rescale when the tile max grew past THR=8 (log2
    // domain, so P bounded by 2^8 — safe in bf16/f32).
    if (!__all(tm <= mrun + 8.f)) {
      float mn = fmaxf(mrun, tm);
      float corr = exp2f(mrun - mn);
      mrun = mn;
      lp *= corr;
#pragma unroll
      for (int df = 0; df < 2; ++df)
#pragma unroll
        for (int r = 0; r < 16; ++r) oacc[df][r] *= corr;
    }

    float a0 = 0.f, a1 = 0.f, a2 = 0.f, a3 = 0.f;
#pragma unroll
    for (int sb = 0; sb < 2; ++sb)
#pragma unroll
      for (int r = 0; r < 16; r += 4) {
        float e0 = exp2f(sacc[sb][r] - mrun);
        float e1 = exp2f(sacc[sb][r + 1] - mrun);
        float e2 = exp2f(sacc[sb][r + 2] - mrun);
        float e3 = exp2f(sacc[sb][r + 3] - mrun);
        sacc[sb][r] = e0; sacc[sb][r + 1] = e1; sacc[sb][r + 2] = e2; sacc[sb][r + 3] = e3;
        a0 += e0; a1 += e1; a2 += e2; a3 += e3;
      }
    lp += (a0 + a1) + (a2 + a3);

    // ---- pack P to B-frag layout: k = ks*16 + hi*8 + j consecutive s ----
    bf16x8 pf[2][2];  // [sb][ks]
#pragma unroll
    for (int sb = 0; sb < 2; ++sb) {
      u32 pw[8];
#pragma unroll
      for (int r2 = 0; r2 < 8; ++r2) {
        u32 o;
        asm("v_cvt_pk_bf16_f32 %0, %1, %2"
            : "=v"(o)
            : "v"(sacc[sb][2 * r2]), "v"(sacc[sb][2 * r2 + 1]));
        pw[r2] = o;
      }
      u32 fw[2][4];
#pragma unroll
      for (int pp = 0; pp < 4; ++pp) {
        int ks = pp >> 1, o = pp & 1;
        u32 a = pw[ks * 4 + o], bq = pw[ks * 4 + o + 2];
        u32 ax = __shfl_xor(a, 32), bx = __shfl_xor(bq, 32);
        fw[ks][o] = hi ? bx : a;
        fw[ks][o + 2] = hi ? bq : ax;
      }
#pragma unroll
      for (int ks = 0; ks < 2; ++ks) {
        i32x4 iv = {(int)fw[ks][0], (int)fw[ks][1], (int)fw[ks][2], (int)fw[ks][3]};
        pf[sb][ks] = __builtin_bit_cast(bf16x8, iv);
      }
    }

    // ---- O^T += Vt * P^T ----
    __builtin_amdgcn_s_setprio(1);
#pragma unroll
    for (int df = 0; df < 2; ++df)
#pragma unroll
      for (int sb = 0; sb < 2; ++sb)
#pragma unroll
        for (int ks = 0; ks < 2; ++ks)
          oacc[df] =
              __builtin_amdgcn_mfma_f32_32x32x16_bf16(vf[df][sb][ks], pf[sb][ks], oacc[df], 0, 0, 0);
    __builtin_amdgcn_s_setprio(0);
  }

  // ---- split merge + epilogue ----
  lp += __shfl_xor(lp, 32);  // full l over this split's keys

  if (spl == 1) {  // publish partials (O^T in frag layout; m,l from hi==0 half)
    float* cb = &cmb[qsub][l31][0];
#pragma unroll
    for (int df = 0; df < 2; ++df)
#pragma unroll
      for (int r = 0; r < 16; ++r) {
        int d = df * 32 + (r & 3) + 8 * (r >> 2) + 4 * hi;
        cb[d] = oacc[df][r];
      }
    if (hi == 0) { cb[64] = mrun; cb[65] = lp; }
  }
  __syncthreads();
  if (spl == 0) {  // merge: stride-66 reads are 2-way bank aliased (free)
    const float* cb = &cmb[qsub][l31][0];
    float mb = cb[64], lb = cb[65];
    float mfin = fmaxf(mrun, mb);
    float ca = exp2f(mrun - mfin), cbf = exp2f(mb - mfin);
    float linv = 1.0f / (ca * lp + cbf * lb);
#pragma unroll
    for (int df = 0; df < 2; ++df)
#pragma unroll
      for (int r = 0; r < 16; ++r) {
        int d = df * 32 + (r & 3) + 8 * (r >> 2) + 4 * hi;
        float o = ca * oacc[df][r] + cbf * cb[d];
        ot[qsub][l31][d] = f2bf(o * linv);
      }
  }
  __syncthreads();
  if (spl == 0) {
    int tr = lane >> 1, dblk = (lane & 1) * 32;
    u16* gdst = Oa + ((size_t)(b * Tt + t0 + tr)) * Dd + h * HD + dblk;
#pragma unroll
    for (int c = 0; c < 4; ++c) {
      ushort8v vv = *reinterpret_cast<const ushort8v*>(&ot[qsub][tr][dblk + c * 8]);
      *reinterpret_cast<ushort8v*>(gdst + c * 8) = vv;
    }
  }
}

// ---------------------------------------------------------------- launch
extern "C" void kernel_launch(void* const* d_in, const int* in_sizes, int n_in, void* d_out,
                              int out_size, void* d_ws, size_t ws_size, hipStream_t stream) {
  (void)in_sizes; (void)n_in; (void)out_size; (void)ws_size;
  const float* x = (const float*)d_in[0];
  const float* cosT = (const float*)d_in[1];
  const float* sinT = (const float*)d_in[2];
  const float* Wq = (const float*)d_in[3];
  const float* Wkv = (const float*)d_in[4];
  const float* Wo = (const float*)d_in[5];

  char* p = (char*)d_ws;
  u16* xb = (u16*)p;   p += (size_t)4096 * 1024 * 2;
  u16* wqkv = (u16*)p; p += (size_t)1536 * 1024 * 2;
  u16* wob = (u16*)p;  p += (size_t)1024 * 1024 * 2;
  u16* Pbuf = (u16*)p; p += (size_t)4096 * 1536 * 2;
  u16* Qb = (u16*)p;   p += (size_t)Bb * QH * Tt * HD * 2;
  u16* Kbuf = (u16*)p; p += (size_t)Bb * KVH * Tt * HD * 2;
  u16* Vtb = (u16*)p;  p += (size_t)Bb * KVH * HD * Tt * 2;
  u16* Ob = Pbuf;  // Pbuf dead after rope_scatter + v_transpose

  cvt_f32_to_bf16<<<4096, 256, 0, stream>>>(x, xb, 1048576);
  cvt_f32_to_bf16<<<1024, 256, 0, stream>>>(Wq, wqkv, 262144);
  cvt_f32_to_bf16<<<512, 256, 0, stream>>>(Wkv, wqkv + (size_t)1024 * 1024, 131072);
  cvt_f32_to_bf16<<<1024, 256, 0, stream>>>(Wo, wob, 262144);

  gemm_bt<false><<<dim3(12, 32), 256, 0, stream>>>(xb, wqkv, Pbuf, 4096, 1536, 1024);
  rope_scatter<<<10240, 256, 0, stream>>>(Pbuf, cosT, sinT, Qb, Kbuf);
  v_transpose<<<dim3(32, 8), 256, 0, stream>>>(Pbuf, Vtb);
  attn_fwd3<<<512, 512, 0, stream>>>(Qb, Kbuf, Vtb, Ob);
  gemm_bt<true><<<dim3(8, 32), 256, 0, stream>>>(Ob, wob, d_out, 4096, 1024, 1024);
}